// Round 3
// baseline (266.769 us; speedup 1.0000x reference)
//
#include <hip/hip_runtime.h>

#define TT 4
#define BB 8
#define CC 256
#define NN 512
#define HEADS 16
#define HD 16

#define GLL16(gp, lp) \
    __builtin_amdgcn_global_load_lds( \
        (const __attribute__((address_space(1))) void*)(gp), \
        (__attribute__((address_space(3))) void*)(lp), 16, 0, 0)

struct WPtrs  { const float* w[4]; };
struct BnPtrs { const float* g[4]; const float* b[4]; const float* m[4]; const float* v[4]; };

// -----------------------------------------------------------------------------
// Prep 1: BN affine (sc, bi) per channel. grid(4), block(256).
// -----------------------------------------------------------------------------
__global__ __launch_bounds__(256)
void prep_bn(BnPtrs p, float* __restrict__ sc, float* __restrict__ bi)
{
    int m = blockIdx.x, c = threadIdx.x;
    float rs = __fdiv_rn(1.0f, __fsqrt_rn(__fadd_rn(p.v[m][c], 1e-5f)));
    float s  = __fmul_rn(p.g[m][c], rs);
    sc[m * CC + c] = s;
    bi[m * CC + c] = __fsub_rn(p.b[m][c], __fmul_rn(p.m[m][c], s));
}

// -----------------------------------------------------------------------------
// Prep 2: transpose 4 weight matrices: wt[m][k][o] = w_m[o][k].
// grid(16,16,4), block(16,16).
// -----------------------------------------------------------------------------
__global__ __launch_bounds__(256)
void transpose_w(WPtrs p, float* __restrict__ wt)
{
    __shared__ float t[16][17];
    const int m  = blockIdx.z;
    const float* w = p.w[m];
    const int o0 = blockIdx.y * 16, k0 = blockIdx.x * 16;
    const int tx = threadIdx.x, ty = threadIdx.y;
    t[ty][tx] = w[(size_t)(o0 + ty) * CC + k0 + tx];
    __syncthreads();
    wt[(size_t)m * CC * CC + (size_t)(k0 + ty) * CC + o0 + tx] = t[tx][ty];
}

// -----------------------------------------------------------------------------
// Kernel 1: fused q/k/v conv + BN + LIF(v_th=1), 2-phase double-buffered.
// grid (8, 4, 24): z = branch*8 + b. block 256 (tx: 16 n-quads, ty: 16 o-quads).
// 32 stages = 4 t x 8 k-tiles (BK=32). STAGE(s+1) issued before compute(s);
// exactly one __syncthreads (vmcnt drain) per stage. Spike packing deferred
// to a single epilogue (nibbles for all 4 t carried in registers).
// -----------------------------------------------------------------------------
__global__ __launch_bounds__(256, 4)
void qkv_conv_bn_lif_pack(const float* __restrict__ x,     // [T,B,C,N]
                          const float* __restrict__ wt,    // [3][C][C] (k-major)
                          const float* __restrict__ scA,   // [4][C]
                          const float* __restrict__ biA,
                          unsigned long long* __restrict__ bits) // [3][T*B*C*8]
{
    __shared__ float W2[2][32][64];          // 2 x 8 KB  [k][o]
    __shared__ float X2[2][32][64];          // 2 x 8 KB  [k][n]
    __shared__ unsigned short Spk[64][16];   // 2 KB (4 t-nibbles per entry)

    const int tid = threadIdx.x;
    const int tx = tid & 15;
    const int ty = tid >> 4;
    const int br = blockIdx.z >> 3;
    const int b  = blockIdx.z & 7;
    const int o0 = blockIdx.y * 64;
    const int n0 = blockIdx.x * 64;

    const float* wtb = wt + (size_t)br * CC * CC;
    unsigned long long* bout = bits + (size_t)br * (TT * BB * CC * 8);

    float sc[4], bi[4];
#pragma unroll
    for (int i = 0; i < 4; ++i) {
        sc[i] = scA[br * CC + o0 + ty * 4 + i];
        bi[i] = biA[br * CC + o0 + ty * 4 + i];
    }

    auto stage = [&](int s, int buf) {
        const int t  = s >> 3;
        const int k0 = (s & 7) * 32;
        const float* xb = x + (size_t)(t * BB + b) * CC * NN;
#pragma unroll
        for (int i = 0; i < 2; ++i) {
            int idx = tid + 256 * i;          // 0..511 -> lds off = idx*16 (linear)
            int row = idx >> 4;               // 0..31
            int cg  = idx & 15;               // 16B col group
            GLL16(&wtb[(size_t)(k0 + row) * CC + o0 + cg * 4], &W2[buf][row][cg * 4]);
            GLL16(&xb [(size_t)(k0 + row) * NN + n0 + cg * 4], &X2[buf][row][cg * 4]);
        }
    };

    float vst[4][4];
    float acc[4][4];
    unsigned int tnib[4] = {0u, 0u, 0u, 0u};
#pragma unroll
    for (int i = 0; i < 4; ++i)
#pragma unroll
        for (int j = 0; j < 4; ++j) { vst[i][j] = 0.0f; acc[i][j] = 0.0f; }

    stage(0, 0);
    __syncthreads();

    int cur = 0;
    for (int s = 0; s < 32; ++s) {
        if (s < 31) stage(s + 1, cur ^ 1);

#pragma unroll 8
        for (int kk = 0; kk < 32; ++kk) {
            float4 wv = *reinterpret_cast<const float4*>(&W2[cur][kk][ty * 4]);
            float4 xv = *reinterpret_cast<const float4*>(&X2[cur][kk][tx * 4]);
#pragma unroll
            for (int i = 0; i < 4; ++i) {
                float wvi = (i == 0) ? wv.x : (i == 1) ? wv.y : (i == 2) ? wv.z : wv.w;
                acc[i][0] = __fmaf_rn(wvi, xv.x, acc[i][0]);
                acc[i][1] = __fmaf_rn(wvi, xv.y, acc[i][1]);
                acc[i][2] = __fmaf_rn(wvi, xv.z, acc[i][2]);
                acc[i][3] = __fmaf_rn(wvi, xv.w, acc[i][3]);
            }
        }

        if ((s & 7) == 7) {
            const int t = s >> 3;
#pragma unroll
            for (int i = 0; i < 4; ++i) {
                unsigned int nib = 0u;
#pragma unroll
                for (int j = 0; j < 4; ++j) {
                    float ybn = __fadd_rn(__fmul_rn(acc[i][j], sc[i]), bi[i]);
                    float h   = __fadd_rn(vst[i][j],
                                          __fmul_rn(__fsub_rn(ybn, vst[i][j]), 0.5f));
                    bool sp = (h >= 1.0f);
                    vst[i][j] = sp ? 0.0f : h;
                    nib |= (sp ? 1u : 0u) << j;
                    acc[i][j] = 0.0f;
                }
                tnib[i] |= nib << (4 * t);
            }
        }

        __syncthreads();   // drains this wave's GLLs (vmcnt 0) + syncs buffers
        cur ^= 1;
    }

    // Epilogue: pack spikes for all 4 t.
#pragma unroll
    for (int i = 0; i < 4; ++i) Spk[ty * 4 + i][tx] = (unsigned short)tnib[i];
    __syncthreads();
    if (tid < 64) {
#pragma unroll
        for (int t = 0; t < 4; ++t) {
            unsigned long long m = 0ULL;
#pragma unroll
            for (int g = 0; g < 16; ++g)
                m |= (unsigned long long)((Spk[tid][g] >> (4 * t)) & 0xF) << (4 * g);
            bout[((size_t)(t * BB + b) * CC + o0 + tid) * 8 + blockIdx.x] = m;
        }
    }
}

// -----------------------------------------------------------------------------
// Kernel 2: attention via M = K^T V (16x16 integer popcounts), Y = 0.25 * Q M.
// Exact integer arithmetic. grid 512 (tb*16+h), block 256.
// -----------------------------------------------------------------------------
__global__ __launch_bounds__(256)
void attn_kernel(const unsigned long long* __restrict__ bq,
                 const unsigned long long* __restrict__ bk,
                 const unsigned long long* __restrict__ bv,
                 float* __restrict__ y) // [32,C,N]
{
    const int blk = blockIdx.x;
    const int h  = blk & 15;
    const int tb = blk >> 4;
    const int tid = threadIdx.x;

    __shared__ unsigned long long kb[16][8], vb[16][8], qb[16][8];
    __shared__ float M[16][16];

    size_t base = ((size_t)tb * CC + h * HD) * 8;
    if (tid < 128) {
        int j = tid >> 3, ch = tid & 7;
        kb[j][ch] = bk[base + j * 8 + ch];
        vb[j][ch] = bv[base + j * 8 + ch];
        qb[j][ch] = bq[base + j * 8 + ch];
    }
    __syncthreads();

    {
        int j = tid >> 4, d = tid & 15;
        int cnt = 0;
#pragma unroll
        for (int ch = 0; ch < 8; ++ch)
            cnt += __popcll(kb[j][ch] & vb[d][ch]);
        M[j][d] = (float)cnt;
    }
    __syncthreads();

    size_t ybase = ((size_t)tb * CC + h * HD) * (size_t)NN;
#pragma unroll
    for (int r = 0; r < 2; ++r) {
        int n = tid + 256 * r;
        int ch = n >> 6, sh = n & 63;
        float acc[16];
#pragma unroll
        for (int d = 0; d < 16; ++d) acc[d] = 0.0f;
#pragma unroll
        for (int j = 0; j < 16; ++j) {
            float bit = (float)((qb[j][ch] >> sh) & 1ULL);
#pragma unroll
            for (int d = 0; d < 16; ++d)
                acc[d] = __fmaf_rn(bit, M[j][d], acc[d]);
        }
#pragma unroll
        for (int d = 0; d < 16; ++d)
            y[ybase + (size_t)d * NN + n] = __fmul_rn(acc[d], 0.25f);
    }
}

// -----------------------------------------------------------------------------
// Kernel 3: attn LIF (v_th=0.5) in-place on y, spikes stored as 1.0f/0.0f.
// grid 512, block 256: one element per thread; all 32 loads hoisted.
// -----------------------------------------------------------------------------
__global__ __launch_bounds__(256)
void attn_lif(float* __restrict__ y)
{
    const int e = blockIdx.x * 256 + threadIdx.x; // < 131072
    float xs[32];
#pragma unroll
    for (int tb = 0; tb < 32; ++tb)
        xs[tb] = y[(size_t)tb * (CC * NN) + e];
    float v = 0.0f;
#pragma unroll
    for (int tb = 0; tb < 32; ++tb) {
        float h = __fadd_rn(v, __fmul_rn(__fsub_rn(xs[tb], v), 0.5f));
        bool sp = (h >= 0.5f);
        y[(size_t)tb * (CC * NN) + e] = sp ? 1.0f : 0.0f;
        v = sp ? 0.0f : h;
    }
}

// -----------------------------------------------------------------------------
// Kernel 4: proj conv on float spikes + BN + final LIF(v_th=1), f32 out.
// Same 2-phase pipelined template. grid (16,4,8) = 512 blocks; 64(o) x 32(n)
// tiles; BK=32; LDS 24 KB. tx: 16 n-pairs, ty: 16 o-quads.
// -----------------------------------------------------------------------------
__global__ __launch_bounds__(256, 4)
void proj_bn_lif(const float* __restrict__ sfl, // [32,C,N] float spikes
                 const float* __restrict__ wt,  // [C][C] k-major (m=3)
                 const float* __restrict__ scA,
                 const float* __restrict__ biA,
                 float* __restrict__ out)
{
    __shared__ float W2[2][32][64];  // 2 x 8 KB [k][o]
    __shared__ float X2[2][32][32];  // 2 x 4 KB [k][n]

    const int tid = threadIdx.x;
    const int tx = tid & 15;
    const int ty = tid >> 4;
    const int b  = blockIdx.z;
    const int o0 = blockIdx.y * 64;
    const int n0 = blockIdx.x * 32;

    float sc[4], bi[4];
#pragma unroll
    for (int i = 0; i < 4; ++i) {
        sc[i] = scA[3 * CC + o0 + ty * 4 + i];
        bi[i] = biA[3 * CC + o0 + ty * 4 + i];
    }

    auto stage = [&](int s, int buf) {
        const int t  = s >> 3;
        const int k0 = (s & 7) * 32;
        const float* sb = sfl + (size_t)(t * BB + b) * CC * NN;
#pragma unroll
        for (int i = 0; i < 2; ++i) {
            int idx = tid + 256 * i;
            int row = idx >> 4, cg = idx & 15;
            GLL16(&wt[(size_t)(k0 + row) * CC + o0 + cg * 4], &W2[buf][row][cg * 4]);
        }
        {
            int row = tid >> 3, cg = tid & 7;   // 32 x 32 floats = 256 x 16B
            GLL16(&sb[(size_t)(k0 + row) * NN + n0 + cg * 4], &X2[buf][row][cg * 4]);
        }
    };

    float vst[4][2], acc[4][2];
#pragma unroll
    for (int i = 0; i < 4; ++i) {
        vst[i][0] = 0.0f; vst[i][1] = 0.0f;
        acc[i][0] = 0.0f; acc[i][1] = 0.0f;
    }

    stage(0, 0);
    __syncthreads();

    int cur = 0;
    for (int s = 0; s < 32; ++s) {
        if (s < 31) stage(s + 1, cur ^ 1);

#pragma unroll 8
        for (int kk = 0; kk < 32; ++kk) {
            float4 wv = *reinterpret_cast<const float4*>(&W2[cur][kk][ty * 4]);
            float2 xv = *reinterpret_cast<const float2*>(&X2[cur][kk][tx * 2]);
#pragma unroll
            for (int i = 0; i < 4; ++i) {
                float wvi = (i == 0) ? wv.x : (i == 1) ? wv.y : (i == 2) ? wv.z : wv.w;
                acc[i][0] = __fmaf_rn(wvi, xv.x, acc[i][0]);
                acc[i][1] = __fmaf_rn(wvi, xv.y, acc[i][1]);
            }
        }

        if ((s & 7) == 7) {
            const int t = s >> 3;
#pragma unroll
            for (int i = 0; i < 4; ++i) {
                float2 o2;
                float r[2];
#pragma unroll
                for (int j = 0; j < 2; ++j) {
                    float ybn = __fadd_rn(__fmul_rn(acc[i][j], sc[i]), bi[i]);
                    float h   = __fadd_rn(vst[i][j],
                                          __fmul_rn(__fsub_rn(ybn, vst[i][j]), 0.5f));
                    bool sp = (h >= 1.0f);
                    vst[i][j] = sp ? 0.0f : h;
                    r[j] = sp ? 1.0f : 0.0f;
                    acc[i][j] = 0.0f;
                }
                o2.x = r[0]; o2.y = r[1];
                *reinterpret_cast<float2*>(
                    &out[((size_t)(t * BB + b) * CC + o0 + ty * 4 + i) * NN + n0 + tx * 2]) = o2;
            }
        }

        __syncthreads();
        cur ^= 1;
    }
}

// -----------------------------------------------------------------------------
extern "C" void kernel_launch(void* const* d_in, const int* in_sizes, int n_in,
                              void* d_out, int out_size, void* d_ws, size_t ws_size,
                              hipStream_t stream) {
    const float* x = (const float*)d_in[0];

    WPtrs wp;
    BnPtrs bp;
    for (int m = 0; m < 4; ++m) {
        wp.w[m] = (const float*)d_in[1 + m * 5 + 0];
        bp.g[m] = (const float*)d_in[1 + m * 5 + 1];
        bp.b[m] = (const float*)d_in[1 + m * 5 + 2];
        bp.m[m] = (const float*)d_in[1 + m * 5 + 3];
        bp.v[m] = (const float*)d_in[1 + m * 5 + 4];
    }

    char* ws = (char*)d_ws;
    float* wt   = (float*)ws;                                    // 1 MB
    float* scA  = (float*)(ws + (1u << 20));                     // 4 KB
    float* biA  = (float*)(ws + (1u << 20) + 4096);              // 4 KB
    unsigned long long* bits = (unsigned long long*)(ws + (1u << 20) + 8192); // 1.5 MB
    float* ybuf = (float*)(ws + (1u << 20) + 8192 + (1536u << 10));           // 16 MB

    prep_bn<<<4, 256, 0, stream>>>(bp, scA, biA);
    transpose_w<<<dim3(16, 16, 4), dim3(16, 16), 0, stream>>>(wp, wt);

    qkv_conv_bn_lif_pack<<<dim3(8, 4, 24), 256, 0, stream>>>(x, wt, scA, biA, bits);

    const unsigned long long* bq = bits;
    const unsigned long long* bk = bits + 65536;
    const unsigned long long* bv = bits + 131072;
    attn_kernel<<<512, 256, 0, stream>>>(bq, bk, bv, ybuf);
    attn_lif<<<512, 256, 0, stream>>>(ybuf);
    proj_bn_lif<<<dim3(16, 4, 8), 256, 0, stream>>>(ybuf, wt + 3 * CC * CC, scA, biA, (float*)d_out);
}